// Round 1
// baseline (180.138 us; speedup 1.0000x reference)
//
#include <hip/hip_runtime.h>

// 3x3 median filter, zero-padded, on (32,3,512,512) fp32.
// One thread computes 4 consecutive output pixels (float4 store).
// Median of 9 via the classic 19-compare-exchange Smith network, run
// component-wise on float4 so all 4 pixels share the network.

#define H 512
#define W 512
#define W4 (W / 4)

__device__ __forceinline__ float4 f4min(float4 a, float4 b) {
    return make_float4(fminf(a.x, b.x), fminf(a.y, b.y), fminf(a.z, b.z), fminf(a.w, b.w));
}
__device__ __forceinline__ float4 f4max(float4 a, float4 b) {
    return make_float4(fmaxf(a.x, b.x), fmaxf(a.y, b.y), fmaxf(a.z, b.z), fmaxf(a.w, b.w));
}

#define MNMX(a, b) { float4 t_ = f4min(a, b); b = f4max(a, b); a = t_; }

__global__ __launch_bounds__(256) void median3x3_kernel(
    const float* __restrict__ in, float* __restrict__ out) {
    int t = blockIdx.x * 256 + threadIdx.x;

    int xq    = t & (W4 - 1);        // which group of 4 columns
    int rest  = t >> 7;              // / W4
    int y     = rest & (H - 1);
    int plane = rest >> 9;           // b*c plane index

    int x0 = xq << 2;
    const float* pbase = in + (size_t)plane * (H * W);

    float4 v[3][3];  // [row dy][shift dx]
#pragma unroll
    for (int i = 0; i < 3; ++i) {
        int yy = y + i - 1;
        float4 m;
        float l, r;
        if (yy >= 0 && yy < H) {
            const float* prow = pbase + (size_t)yy * W;
            m = *(const float4*)(prow + x0);
            l = (x0 > 0)     ? prow[x0 - 1] : 0.0f;
            r = (x0 + 4 < W) ? prow[x0 + 4] : 0.0f;
        } else {
            m = make_float4(0.f, 0.f, 0.f, 0.f);
            l = 0.f;
            r = 0.f;
        }
        v[i][0] = make_float4(l, m.x, m.y, m.z);   // columns x-1 .. x+2
        v[i][1] = m;                               // columns x   .. x+3
        v[i][2] = make_float4(m.y, m.z, m.w, r);   // columns x+1 .. x+4
    }

    float4 p0 = v[0][0], p1 = v[0][1], p2 = v[0][2];
    float4 p3 = v[1][0], p4 = v[1][1], p5 = v[1][2];
    float4 p6 = v[2][0], p7 = v[2][1], p8 = v[2][2];

    // Smith 19-exchange median-of-9 network; median lands in p4.
    MNMX(p1, p2); MNMX(p4, p5); MNMX(p7, p8);
    MNMX(p0, p1); MNMX(p3, p4); MNMX(p6, p7);
    MNMX(p1, p2); MNMX(p4, p5); MNMX(p7, p8);
    MNMX(p0, p3); MNMX(p5, p8); MNMX(p4, p7);
    MNMX(p3, p6); MNMX(p1, p4); MNMX(p2, p5);
    MNMX(p4, p7); MNMX(p4, p2); MNMX(p6, p4);
    MNMX(p4, p2);

    float* orow = out + (size_t)plane * (H * W) + (size_t)y * W + x0;
    *(float4*)orow = p4;
}

extern "C" void kernel_launch(void* const* d_in, const int* in_sizes, int n_in,
                              void* d_out, int out_size, void* d_ws, size_t ws_size,
                              hipStream_t stream) {
    const float* x = (const float*)d_in[0];
    float* out = (float*)d_out;

    // out_size = 32*3*512*512 = 25165824; each thread writes 4 elements.
    int threads_total = out_size / 4;              // 6,291,456
    int blocks = threads_total / 256;              // 24,576 (exact)
    median3x3_kernel<<<dim3(blocks), dim3(256), 0, stream>>>(x, out);
}

// Round 2
// 174.404 us; speedup vs baseline: 1.0329x; 1.0329x over previous
//
#include <hip/hip_runtime.h>

// 3x3 median filter, zero-padded, (32,3,512,512) fp32.
// Each thread: 4 columns x 8 rows (one float4 store per row).
// Median-of-9 via exact identity over 3 sorted horizontal triples:
//   med9 = med3( max3(mins), med3(meds), min3(maxes) )
// using gfx950 single-instruction v_min3/v_med3/v_max3.

#define H 512
#define W 512
#define ROWS 8
#define STRIPS (H / ROWS)   // 64
#define W4 (W / 4)          // 128

__device__ __forceinline__ float f_min3(float a, float b, float c) { return fminf(fminf(a, b), c); }
__device__ __forceinline__ float f_max3(float a, float b, float c) { return fmaxf(fmaxf(a, b), c); }
__device__ __forceinline__ float f_med3(float a, float b, float c) { return __builtin_amdgcn_fmed3f(a, b, c); }

__global__ __launch_bounds__(256) void median3x3_kernel(const float* __restrict__ in,
                                                        float* __restrict__ out) {
    int t = blockIdx.x * 256 + threadIdx.x;
    int xq    = t & (W4 - 1);           // column group (4 cols)
    int strip = (t >> 7) & (STRIPS - 1);
    int plane = t >> 13;                // b*c plane

    int x0 = xq << 2;
    int ybase = strip * ROWS;
    const float* pbase = in + (size_t)plane * (H * W);

    // rs[i][j]: input row (ybase-1+i), columns x0-1 .. x0+4
    float rs[ROWS + 2][6];
#pragma unroll
    for (int i = 0; i < ROWS + 2; ++i) {
        int yy = ybase + i - 1;
        if (yy >= 0 && yy < H) {        // wave-uniform branch (strip uniform per wave)
            const float* prow = pbase + (size_t)yy * W;
            float4 m = *(const float4*)(prow + x0);
            rs[i][0] = (x0 > 0) ? prow[x0 - 1] : 0.0f;
            rs[i][1] = m.x; rs[i][2] = m.y; rs[i][3] = m.z; rs[i][4] = m.w;
            rs[i][5] = (x0 + 4 < W) ? prow[x0 + 4] : 0.0f;
        } else {
#pragma unroll
            for (int j = 0; j < 6; ++j) rs[i][j] = 0.0f;
        }
    }

    float* obase = out + (size_t)plane * (H * W) + (size_t)ybase * W + x0;
#pragma unroll
    for (int r = 0; r < ROWS; ++r) {
        float res[4];
#pragma unroll
        for (int j = 0; j < 4; ++j) {
            // sorted horizontal triples of the 3 contributing rows
            // (compiler CSEs these across the unrolled r-loop: each row's
            //  sort3 is shared by the 3 output rows that use it)
            float l0 = f_min3(rs[r    ][j], rs[r    ][j + 1], rs[r    ][j + 2]);
            float m0 = f_med3(rs[r    ][j], rs[r    ][j + 1], rs[r    ][j + 2]);
            float h0 = f_max3(rs[r    ][j], rs[r    ][j + 1], rs[r    ][j + 2]);
            float l1 = f_min3(rs[r + 1][j], rs[r + 1][j + 1], rs[r + 1][j + 2]);
            float m1 = f_med3(rs[r + 1][j], rs[r + 1][j + 1], rs[r + 1][j + 2]);
            float h1 = f_max3(rs[r + 1][j], rs[r + 1][j + 1], rs[r + 1][j + 2]);
            float l2 = f_min3(rs[r + 2][j], rs[r + 2][j + 1], rs[r + 2][j + 2]);
            float m2 = f_med3(rs[r + 2][j], rs[r + 2][j + 1], rs[r + 2][j + 2]);
            float h2 = f_max3(rs[r + 2][j], rs[r + 2][j + 1], rs[r + 2][j + 2]);
            res[j] = f_med3(f_max3(l0, l1, l2), f_med3(m0, m1, m2), f_min3(h0, h1, h2));
        }
        *(float4*)(obase + (size_t)r * W) = make_float4(res[0], res[1], res[2], res[3]);
    }
}

extern "C" void kernel_launch(void* const* d_in, const int* in_sizes, int n_in,
                              void* d_out, int out_size, void* d_ws, size_t ws_size,
                              hipStream_t stream) {
    const float* x = (const float*)d_in[0];
    float* out = (float*)d_out;

    // out_size = 32*3*512*512 = 25,165,824; each thread writes 4*8 = 32 elems.
    int threads_total = out_size / 32;   // 786,432
    int blocks = threads_total / 256;    // 3,072 (exact)
    median3x3_kernel<<<dim3(blocks), dim3(256), 0, stream>>>(x, out);
}

// Round 3
// 173.868 us; speedup vs baseline: 1.0361x; 1.0031x over previous
//
#include <hip/hip_runtime.h>

// 3x3 median filter, zero-padded, (32,3,512,512) fp32.
// One wave (64 lanes) covers a full 512-col row: lane owns 8 contiguous
// columns (two float4 loads, fully coalesced). Horizontal halos come from
// neighbor lanes via __shfl (no scalar gather loads). Each thread computes
// ROWS=4 output rows from a 6-row register window.
// Median-of-9 = med3(max3(row mins), med3(row meds), min3(row maxes))
// over sorted horizontal triples (exact; single-instr v_min3/med3/max3).

#define H 512
#define W 512
#define ROWS 4
#define STRIPS (H / ROWS)   // 128

__device__ __forceinline__ float f_min3(float a, float b, float c) { return fminf(fminf(a, b), c); }
__device__ __forceinline__ float f_max3(float a, float b, float c) { return fmaxf(fmaxf(a, b), c); }
__device__ __forceinline__ float f_med3(float a, float b, float c) { return __builtin_amdgcn_fmed3f(a, b, c); }

__global__ __launch_bounds__(256) void median3x3_kernel(const float* __restrict__ in,
                                                        float* __restrict__ out) {
    int t = blockIdx.x * 256 + threadIdx.x;
    int lane  = t & 63;                  // column group: cols lane*8 .. lane*8+7
    int strip = (t >> 6) & (STRIPS - 1);
    int plane = t >> 13;                 // b*c plane (96)

    int x0 = lane << 3;
    int ybase = strip * ROWS;
    const float* pbase = in + (size_t)plane * (H * W);

    // Register window: input rows ybase-1 .. ybase+ROWS, 8 cols each.
    float raw[ROWS + 2][8];
#pragma unroll
    for (int i = 0; i < ROWS + 2; ++i) {
        int yy = ybase + i - 1;
        if (yy >= 0 && yy < H) {         // wave-uniform (strip uniform per wave)
            const float* prow = pbase + (size_t)yy * W + x0;
            float4 a = *(const float4*)prow;
            float4 b = *(const float4*)(prow + 4);
            raw[i][0] = a.x; raw[i][1] = a.y; raw[i][2] = a.z; raw[i][3] = a.w;
            raw[i][4] = b.x; raw[i][5] = b.y; raw[i][6] = b.z; raw[i][7] = b.w;
        } else {
#pragma unroll
            for (int j = 0; j < 8; ++j) raw[i][j] = 0.0f;
        }
    }

    // Horizontal halos from neighbor lanes (image border -> 0, matching zero-pad).
    float hl[ROWS + 2], hr[ROWS + 2];
#pragma unroll
    for (int i = 0; i < ROWS + 2; ++i) {
        float l = __shfl_up(raw[i][7], 1);
        hl[i] = (lane == 0) ? 0.0f : l;
        float r = __shfl_down(raw[i][0], 1);
        hr[i] = (lane == 63) ? 0.0f : r;
    }

    float* obase = out + (size_t)plane * (H * W) + (size_t)ybase * W + x0;
#pragma unroll
    for (int r = 0; r < ROWS; ++r) {
        float res[8];
#pragma unroll
        for (int j = 0; j < 8; ++j) {
            float a0 = (j == 0) ? hl[r]     : raw[r][j - 1];
            float a1 = raw[r][j];
            float a2 = (j == 7) ? hr[r]     : raw[r][j + 1];
            float b0 = (j == 0) ? hl[r + 1] : raw[r + 1][j - 1];
            float b1 = raw[r + 1][j];
            float b2 = (j == 7) ? hr[r + 1] : raw[r + 1][j + 1];
            float c0 = (j == 0) ? hl[r + 2] : raw[r + 2][j - 1];
            float c1 = raw[r + 2][j];
            float c2 = (j == 7) ? hr[r + 2] : raw[r + 2][j + 1];
            // sorted triples (compiler CSEs across the 3 output rows sharing a row)
            float l0 = f_min3(a0, a1, a2), m0 = f_med3(a0, a1, a2), h0 = f_max3(a0, a1, a2);
            float l1 = f_min3(b0, b1, b2), m1 = f_med3(b0, b1, b2), h1 = f_max3(b0, b1, b2);
            float l2 = f_min3(c0, c1, c2), m2 = f_med3(c0, c1, c2), h2 = f_max3(c0, c1, c2);
            res[j] = f_med3(f_max3(l0, l1, l2), f_med3(m0, m1, m2), f_min3(h0, h1, h2));
        }
        float* orow = obase + (size_t)r * W;
        *(float4*)orow       = make_float4(res[0], res[1], res[2], res[3]);
        *(float4*)(orow + 4) = make_float4(res[4], res[5], res[6], res[7]);
    }
}

extern "C" void kernel_launch(void* const* d_in, const int* in_sizes, int n_in,
                              void* d_out, int out_size, void* d_ws, size_t ws_size,
                              hipStream_t stream) {
    const float* x = (const float*)d_in[0];
    float* out = (float*)d_out;

    // out_size = 32*3*512*512; each thread writes 8 cols * 4 rows = 32 elems.
    int threads_total = out_size / 32;   // 786,432
    int blocks = threads_total / 256;    // 3,072 (exact)
    median3x3_kernel<<<dim3(blocks), dim3(256), 0, stream>>>(x, out);
}

// Round 4
// 172.899 us; speedup vs baseline: 1.0419x; 1.0056x over previous
//
#include <hip/hip_runtime.h>

// 3x3 median filter, zero-padded, (32,3,512,512) fp32.
// One wave spans a full 512-col row via TWO DENSE half-rows:
//   group A = cols lane*4 .. lane*4+3        (bytes: lane*16, dense)
//   group B = cols 256+lane*4 .. 256+lane*4+3 (dense)
// All loads/stores are fully-coalesced 16B/lane dense float4 ops.
// Horizontal halos entirely via __shfl within the wave:
//   A-left  = shfl_up(A[3])   (lane0 -> 0, image border)
//   A-right = shfl_down(A[0]) (lane63 -> broadcast lane0's B[0], col 256)
//   B-left  = shfl_up(B[3])   (lane0 -> broadcast lane63's A[3], col 255)
//   B-right = shfl_down(B[0]) (lane63 -> 0, image border)
// Median-of-9 = med3(max3(row mins), med3(row meds), min3(row maxes))
// over sorted horizontal triples (exact; v_min3/v_med3/v_max3).

#define H 512
#define W 512
#define ROWS 4
#define STRIPS (H / ROWS)   // 128

__device__ __forceinline__ float f_min3(float a, float b, float c) { return fminf(fminf(a, b), c); }
__device__ __forceinline__ float f_max3(float a, float b, float c) { return fmaxf(fmaxf(a, b), c); }
__device__ __forceinline__ float f_med3(float a, float b, float c) { return __builtin_amdgcn_fmed3f(a, b, c); }

__global__ __launch_bounds__(256, 4) void median3x3_kernel(const float* __restrict__ in,
                                                           float* __restrict__ out) {
    int t = blockIdx.x * 256 + threadIdx.x;
    int lane  = t & 63;
    int strip = (t >> 6) & (STRIPS - 1);
    int plane = t >> 13;                 // 96 planes

    int ybase = strip * ROWS;
    int xA = lane << 2;                  // dense half 0
    const float* pbase = in + (size_t)plane * (H * W);

    // Register window: rows ybase-1 .. ybase+ROWS; A/B = the two half-rows.
    float A[ROWS + 2][4], B[ROWS + 2][4];
#pragma unroll
    for (int i = 0; i < ROWS + 2; ++i) {
        int yy = ybase + i - 1;
        if (yy >= 0 && yy < H) {         // wave-uniform (strip uniform per wave)
            const float* prow = pbase + (size_t)yy * W;
            float4 a = *(const float4*)(prow + xA);
            float4 b = *(const float4*)(prow + 256 + xA);
            A[i][0] = a.x; A[i][1] = a.y; A[i][2] = a.z; A[i][3] = a.w;
            B[i][0] = b.x; B[i][1] = b.y; B[i][2] = b.z; B[i][3] = b.w;
        } else {
#pragma unroll
            for (int j = 0; j < 4; ++j) { A[i][j] = 0.0f; B[i][j] = 0.0f; }
        }
    }

    // Halos (all in-wave; borders are true zeros).
    float Al[ROWS + 2], Ar[ROWS + 2], Bl[ROWS + 2], Br[ROWS + 2];
#pragma unroll
    for (int i = 0; i < ROWS + 2; ++i) {
        float al = __shfl_up(A[i][3], 1);
        float ar = __shfl_down(A[i][0], 1);
        float bl = __shfl_up(B[i][3], 1);
        float br = __shfl_down(B[i][0], 1);
        float b0w0  = __shfl(B[i][0], 0);    // col 256 (for lane 63's A-right)
        float a3w63 = __shfl(A[i][3], 63);   // col 255 (for lane 0's B-left)
        Al[i] = (lane == 0)  ? 0.0f  : al;
        Ar[i] = (lane == 63) ? b0w0  : ar;
        Bl[i] = (lane == 0)  ? a3w63 : bl;
        Br[i] = (lane == 63) ? 0.0f  : br;
    }

    float* obase = out + (size_t)plane * (H * W) + (size_t)ybase * W + xA;
#pragma unroll
    for (int r = 0; r < ROWS; ++r) {
        float resA[4], resB[4];
#pragma unroll
        for (int j = 0; j < 4; ++j) {
            // group A, column j: neighbors within (Al, A[0..3], Ar)
            float a0 = (j == 0) ? Al[r]     : A[r][j - 1];
            float a1 = A[r][j];
            float a2 = (j == 3) ? Ar[r]     : A[r][j + 1];
            float b0 = (j == 0) ? Al[r + 1] : A[r + 1][j - 1];
            float b1 = A[r + 1][j];
            float b2 = (j == 3) ? Ar[r + 1] : A[r + 1][j + 1];
            float c0 = (j == 0) ? Al[r + 2] : A[r + 2][j - 1];
            float c1 = A[r + 2][j];
            float c2 = (j == 3) ? Ar[r + 2] : A[r + 2][j + 1];
            float l0 = f_min3(a0, a1, a2), m0 = f_med3(a0, a1, a2), h0 = f_max3(a0, a1, a2);
            float l1 = f_min3(b0, b1, b2), m1 = f_med3(b0, b1, b2), h1 = f_max3(b0, b1, b2);
            float l2 = f_min3(c0, c1, c2), m2 = f_med3(c0, c1, c2), h2 = f_max3(c0, c1, c2);
            resA[j] = f_med3(f_max3(l0, l1, l2), f_med3(m0, m1, m2), f_min3(h0, h1, h2));

            // group B, column j
            float d0 = (j == 0) ? Bl[r]     : B[r][j - 1];
            float d1 = B[r][j];
            float d2 = (j == 3) ? Br[r]     : B[r][j + 1];
            float e0 = (j == 0) ? Bl[r + 1] : B[r + 1][j - 1];
            float e1 = B[r + 1][j];
            float e2 = (j == 3) ? Br[r + 1] : B[r + 1][j + 1];
            float g0 = (j == 0) ? Bl[r + 2] : B[r + 2][j - 1];
            float g1 = B[r + 2][j];
            float g2 = (j == 3) ? Br[r + 2] : B[r + 2][j + 1];
            float l3 = f_min3(d0, d1, d2), m3 = f_med3(d0, d1, d2), h3 = f_max3(d0, d1, d2);
            float l4 = f_min3(e0, e1, e2), m4 = f_med3(e0, e1, e2), h4 = f_max3(e0, e1, e2);
            float l5 = f_min3(g0, g1, g2), m5 = f_med3(g0, g1, g2), h5 = f_max3(g0, g1, g2);
            resB[j] = f_med3(f_max3(l3, l4, l5), f_med3(m3, m4, m5), f_min3(h3, h4, h5));
        }
        float* orow = obase + (size_t)r * W;
        *(float4*)orow         = make_float4(resA[0], resA[1], resA[2], resA[3]);
        *(float4*)(orow + 256) = make_float4(resB[0], resB[1], resB[2], resB[3]);
    }
}

extern "C" void kernel_launch(void* const* d_in, const int* in_sizes, int n_in,
                              void* d_out, int out_size, void* d_ws, size_t ws_size,
                              hipStream_t stream) {
    const float* x = (const float*)d_in[0];
    float* out = (float*)d_out;

    // out_size = 32*3*512*512; each thread writes 8 cols * 4 rows = 32 elems.
    int threads_total = out_size / 32;   // 786,432
    int blocks = threads_total / 256;    // 3,072 (exact)
    median3x3_kernel<<<dim3(blocks), dim3(256), 0, stream>>>(x, out);
}